// Round 17
// baseline (1306.692 us; speedup 1.0000x reference)
//
#include <hip/hip_runtime.h>

// ODE-GRU on MI355X, round 17.
// 256 blocks x 1024 threads, dual-row + quarter-split. Thread t: element
// j=t>>2, quarter p2=t&3, handles BOTH batch rows (2*blk, 2*blk+1).
// Satisfies all three empirically-derived constraints:
//  (1) weight stream issued ONCE per CU per step (r12/r14: 2x streams fatal);
//  (2) live VGPRs ~80 << 128 cap (5 spill failures at >~100);
//  (3) dual-row register amortization kept (r13's 2.5x win).
// vs r16: same fdot2/loads/LDS-bytes per CU, but 16 waves/CU instead of 8
// (quarter-split halves per-thread work). +1 DPP stage per reduction.
// Drift: forward Euler (validated r16), 3 barriers/step. DPP chains
// 0xB1/0x4E/0x141/0x140 all refcheck-validated in r10.
// Tripwires: FETCH ~2e4 KB, WRITE ~1.3e5 KB, absmax 0.00390625.

#define SEQ   256
#define BATCH 512
#define DIN   54
#define HDIM  256
#define DH    64

typedef _Float16 h2 __attribute__((ext_vector_type(2)));
typedef _Float16 h8 __attribute__((ext_vector_type(8)));

#define PX(v, p) __builtin_shufflevector((v), (v), 2*(p), 2*(p)+1)

#if defined(__has_builtin)
#  if __has_builtin(__builtin_amdgcn_fdot2)
#    define FDOT2(a, b, c) __builtin_amdgcn_fdot2((a), (b), (c), false)
#  endif
#endif
#ifndef FDOT2
#  define FDOT2(a, b, c) fmaf((float)(a)[0], (float)(b)[0], \
                         fmaf((float)(a)[1], (float)(b)[1], (c)))
#endif

__device__ __forceinline__ float rcp_f(float x) { return __builtin_amdgcn_rcpf(x); }

__device__ __forceinline__ float fast_tanh(float x) {
    x = fminf(15.0f, fmaxf(-15.0f, x));
    float e = __expf(2.0f * x);
    return 1.0f - 2.0f * rcp_f(e + 1.0f);
}
__device__ __forceinline__ float fast_sigmoid(float x) {
    x = fminf(30.0f, fmaxf(-30.0f, x));
    return rcp_f(1.0f + __expf(-x));
}

// x + dpp_permute(x): cross-lane add at VALU latency.
// 0xB1 quad_perm lane^1; 0x4E quad_perm lane^2; 0x141 row_half_mirror
// (8-lane finisher once quad-uniform); 0x140 row_mirror (16-lane finisher
// once 8-uniform). All validated r10 (refcheck passed).
template <int CTRL>
__device__ __forceinline__ float dppadd(float x) {
    return x + __int_as_float(
        __builtin_amdgcn_mov_dpp(__float_as_int(x), CTRL, 0xF, 0xF, true));
}

// 4 dot2: accumulate h8 W . h8 Y into A
#define DOT8(A, W, Y) { \
    A = FDOT2(PX(W,0), PX(Y,0), A); A = FDOT2(PX(W,1), PX(Y,1), A); \
    A = FDOT2(PX(W,2), PX(Y,2), A); A = FDOT2(PX(W,3), PX(Y,3), A); }

// ---- prep: f16 GRU weights, [gate][chunk][thread-of-1024] coalesced ----
// WHx: 24576 h8. id = g*8192 + q*1024 + t ; W_hh[(t>>2)+256g][(t&3)*64+q*8 ..+8]
//      (q = 0..7)
// WIx:  6144 h8. id = g*2048 + q*1024 + t ; W_ih[(t>>2)+256g][(t&3)*16+q*8 ..+8]
//      (q = 0..1; cols >= 54 zero-padded)
__global__ __launch_bounds__(256)
void prep_kernel(const float* __restrict__ W_ih, const float* __restrict__ W_hh,
                 h8* __restrict__ WHx, h8* __restrict__ WIx)
{
    const int id = blockIdx.x * 256 + threadIdx.x;
    if (id < 24576) {
        const int g = id >> 13, rem = id & 8191;
        const int q = rem >> 10, t = rem & 1023;
        const int j = t >> 2, p2 = t & 3;
        const float* src = W_hh + (size_t)(j + 256 * g) * HDIM + p2 * 64 + q * 8;
        h8 v;
        #pragma unroll
        for (int e = 0; e < 8; ++e) v[e] = (_Float16)src[e];
        WHx[id] = v;
    } else if (id < 24576 + 6144) {
        const int id2 = id - 24576;
        const int g = id2 >> 11, rem = id2 & 2047;
        const int q = rem >> 10, t = rem & 1023;
        const int j = t >> 2, p2 = t & 3;
        h8 v;
        #pragma unroll
        for (int e = 0; e < 8; ++e) {
            const int col = p2 * 16 + q * 8 + e;
            v[e] = (col < DIN) ? (_Float16)W_ih[(size_t)(j + 256 * g) * DIN + col]
                               : (_Float16)0.0f;
        }
        WIx[id2] = v;
    }
}

__global__ void
__attribute__((amdgpu_flat_work_group_size(1024, 1024), amdgpu_waves_per_eu(4, 4)))
odegru_kernel(const float* __restrict__ x,
              const float* __restrict__ tvec,
              const float* __restrict__ b_ih,
              const float* __restrict__ b_hh,
              const float* __restrict__ W1,
              const float* __restrict__ b1,
              const float* __restrict__ W2,
              const float* __restrict__ b2,
              const h8* __restrict__ WHx,
              const h8* __restrict__ WIx,
              float* __restrict__ out)
{
    const int t   = threadIdx.x;         // 0..1023
    const int b0  = blockIdx.x * 2;      // batch row A
    const int bB  = b0 + 1;              // batch row B
    const int j   = t >> 2;              // element 0..255
    const int p2  = t & 3;               // quarter
    const int i1  = t >> 4;              // drift stage1 output 0..63
    const int k16 = t & 15;              // stage1 k-chunk

    __shared__ __align__(16) _Float16 yG0[HDIM], yG1[HDIM];   // GRU-input y
    __shared__ __align__(16) _Float16 yh0[HDIM], yh1[HDIM];   // drift y
    __shared__ __align__(16) _Float16 uh0[DH],  uh1[DH];
    __shared__ __align__(16) _Float16 xh0[64],  xh1[64];

    // Drift weights -> 4 named h8 vars (16 VGPRs), shared by both rows.
    // w1a/b: W1[i1][k16*8], W1[i1][k16*8+128] ; w2a/b: W2[j][p2*16 (+8)]
    h8 w1a, w1b, w2a, w2b;
    {
        const float* base = W1 + (size_t)i1 * HDIM + k16 * 8;
        h8 v;
        #pragma unroll
        for (int e = 0; e < 8; ++e) v[e] = (_Float16)base[e];       w1a = v;
        #pragma unroll
        for (int e = 0; e < 8; ++e) v[e] = (_Float16)base[e + 128]; w1b = v;
    }
    {
        const float* base = W2 + (size_t)j * DH + p2 * 16;
        h8 v;
        #pragma unroll
        for (int e = 0; e < 8; ++e) v[e] = (_Float16)base[e];       w2a = v;
        #pragma unroll
        for (int e = 0; e < 8; ++e) v[e] = (_Float16)base[e + 8];   w2b = v;
    }

    const float b1r  = b1[i1];
    const float b2r  = b2[j];
    const float bihr = b_ih[j], bihz = b_ih[j + HDIM], bihn = b_ih[j + 2 * HDIM];
    const float bhhr = b_hh[j], bhhz = b_hh[j + HDIM], bhhn = b_hh[j + 2 * HDIM];

    float h0 = 0.0f, h1 = 0.0f;

    for (int i = 0; i < SEQ; ++i) {
        const int s = SEQ - 1 - i;

        if (t < 64) {
            xh0[t] = (t < DIN) ? (_Float16)x[((size_t)s * BATCH + b0) * DIN + t]
                               : (_Float16)0.0f;
        } else if (t < 128) {
            const int u = t - 64;
            xh1[u] = (u < DIN) ? (_Float16)x[((size_t)s * BATCH + bB) * DIN + u]
                               : (_Float16)0.0f;
        }
        if (p2 == 0) { yG0[j] = (_Float16)h0; yG1[j] = (_Float16)h1; }
        __syncthreads();                                   // B1 (top)

        // ---- GRU: quarter-split, each weight load feeds BOTH rows ----
        float xr0 = 0.f, xz0 = 0.f, xn0 = 0.f;
        float xr1 = 0.f, xz1 = 0.f, xn1 = 0.f;
        #pragma unroll
        for (int q = 0; q < 2; ++q) {
            h8 wr = WIx[(0 * 2 + q) * 1024 + t];
            h8 wz = WIx[(1 * 2 + q) * 1024 + t];
            h8 wn = WIx[(2 * 2 + q) * 1024 + t];
            h8 xv0 = *(const h8*)(xh0 + p2 * 16 + q * 8);
            h8 xv1 = *(const h8*)(xh1 + p2 * 16 + q * 8);
            DOT8(xr0, wr, xv0) DOT8(xr1, wr, xv1)
            DOT8(xz0, wz, xv0) DOT8(xz1, wz, xv1)
            DOT8(xn0, wn, xv0) DOT8(xn1, wn, xv1)
        }
        float hr0 = 0.f, hz0 = 0.f, hn0 = 0.f;
        float hr1 = 0.f, hz1 = 0.f, hn1 = 0.f;
        #pragma unroll 2
        for (int q = 0; q < 8; ++q) {
            h8 wr = WHx[(0 * 8 + q) * 1024 + t];
            h8 wz = WHx[(1 * 8 + q) * 1024 + t];
            h8 wn = WHx[(2 * 8 + q) * 1024 + t];
            h8 yv0 = *(const h8*)(yG0 + p2 * 64 + q * 8);
            h8 yv1 = *(const h8*)(yG1 + p2 * 64 + q * 8);
            DOT8(hr0, wr, yv0) DOT8(hr1, wr, yv1)
            DOT8(hz0, wz, yv0) DOT8(hz1, wz, yv1)
            DOT8(hn0, wn, yv0) DOT8(hn1, wn, yv1)
        }
        {
            float Rp = dppadd<0x4E>(dppadd<0xB1>(xr0 + hr0));
            float Zp = dppadd<0x4E>(dppadd<0xB1>(xz0 + hz0));
            float Ip = dppadd<0x4E>(dppadd<0xB1>(xn0));
            float Hp = dppadd<0x4E>(dppadd<0xB1>(hn0));
            float r_g = fast_sigmoid(Rp + bihr + bhhr);
            float z_g = fast_sigmoid(Zp + bihz + bhhz);
            float n_g = fast_tanh(Ip + bihn + r_g * (Hp + bhhn));
            h0 = n_g + z_g * (h0 - n_g);
        }
        {
            float Rp = dppadd<0x4E>(dppadd<0xB1>(xr1 + hr1));
            float Zp = dppadd<0x4E>(dppadd<0xB1>(xz1 + hz1));
            float Ip = dppadd<0x4E>(dppadd<0xB1>(xn1));
            float Hp = dppadd<0x4E>(dppadd<0xB1>(hn1));
            float r_g = fast_sigmoid(Rp + bihr + bhhr);
            float z_g = fast_sigmoid(Zp + bihz + bhhz);
            float n_g = fast_tanh(Ip + bihn + r_g * (Hp + bhhn));
            h1 = n_g + z_g * (h1 - n_g);
        }
        // no barrier: drift writes yh* (not yG*); yG* WAR gap spans B2+B3.

        // ---- ODE integrate: forward Euler (1 dual-row drift) ----
        const float t0v = tvec[s];
        const float t1v = (s > 0) ? tvec[s - 1] : tvec[0];
        const float dt  = (t1v - t0v);

        if (dt != 0.0f) {   // block-uniform; dt==0 only at s==0 (exact skip)
            if (p2 == 0) { yh0[j] = (_Float16)h0; yh1[j] = (_Float16)h1; }
            __syncthreads();                               // B2
            // Stage1: 16-lane group (i1) dots interleaved slices
            // {k16*8, k16*8+128}; 2-way bank aliases only (free).
            float a00 = 0.f, a01 = 0.f, a10 = 0.f, a11 = 0.f;
            {
                h8 v;
                v = *(const h8*)(yh0 + k16 * 8);       DOT8(a00, w1a, v)
                v = *(const h8*)(yh0 + k16 * 8 + 128); DOT8(a01, w1b, v)
                v = *(const h8*)(yh1 + k16 * 8);       DOT8(a10, w1a, v)
                v = *(const h8*)(yh1 + k16 * 8 + 128); DOT8(a11, w1b, v)
            }
            float as0 = a00 + a01, as1 = a10 + a11;
            as0 = dppadd<0xB1>(as0);  as1 = dppadd<0xB1>(as1);
            as0 = dppadd<0x4E>(as0);  as1 = dppadd<0x4E>(as1);
            as0 = dppadd<0x141>(as0); as1 = dppadd<0x141>(as1);
            as0 = dppadd<0x140>(as0); as1 = dppadd<0x140>(as1);
            float uu0 = fast_tanh(as0 + b1r);
            float uu1 = fast_tanh(as1 + b1r);
            if (k16 == 0) { uh0[i1] = (_Float16)uu0; uh1[i1] = (_Float16)uu1; }
            __syncthreads();                               // B3
            // Stage2: quarter p2 covers u[p2*16 ..+16); xor1+xor2 completes.
            float c00 = 0.f, c01 = 0.f, c10 = 0.f, c11 = 0.f;
            {
                h8 u;
                u = *(const h8*)(uh0 + p2 * 16);     DOT8(c00, w2a, u)
                u = *(const h8*)(uh0 + p2 * 16 + 8); DOT8(c01, w2b, u)
                u = *(const h8*)(uh1 + p2 * 16);     DOT8(c10, w2a, u)
                u = *(const h8*)(uh1 + p2 * 16 + 8); DOT8(c11, w2b, u)
            }
            float cs0 = c00 + c01, cs1 = c10 + c11;
            cs0 = dppadd<0xB1>(cs0); cs1 = dppadd<0xB1>(cs1);
            cs0 = dppadd<0x4E>(cs0); cs1 = dppadd<0x4E>(cs1);
            h0 = fmaf(dt, cs0 + b2r, h0);
            h1 = fmaf(dt, cs1 + b2r, h1);
        } else {
            __syncthreads();   // degenerate dt: keep next-step writes ordered
        }

        if (p2 == 0) {
            __builtin_nontemporal_store(h0, &out[((size_t)s * BATCH + b0) * HDIM + j]);
            __builtin_nontemporal_store(h1, &out[((size_t)s * BATCH + bB) * HDIM + j]);
        }
        // no bottom barrier: next top's yG*/xh* writes WAR-safe (gap spans
        // B2+B3); yh*/uh* gaps span B3+B1 / B1+B2 respectively.
    }
}

extern "C" void kernel_launch(void* const* d_in, const int* in_sizes, int n_in,
                              void* d_out, int out_size, void* d_ws, size_t ws_size,
                              hipStream_t stream) {
    const float* x    = (const float*)d_in[0];
    const float* tvec = (const float*)d_in[1];
    const float* W_ih = (const float*)d_in[2];
    const float* W_hh = (const float*)d_in[3];
    const float* b_ih = (const float*)d_in[4];
    const float* b_hh = (const float*)d_in[5];
    const float* W1   = (const float*)d_in[6];
    const float* b1   = (const float*)d_in[7];
    const float* W2   = (const float*)d_in[8];
    const float* b2   = (const float*)d_in[9];
    float* out = (float*)d_out;

    h8* WHx = (h8*)d_ws;                                   // 24576*16 = 393216 B
    h8* WIx = (h8*)((char*)d_ws + 24576 * 16);             //  6144*16 =  98304 B

    hipLaunchKernelGGL(prep_kernel, dim3(120), dim3(256), 0, stream,
                       W_ih, W_hh, WHx, WIx);
    hipLaunchKernelGGL(odegru_kernel, dim3(BATCH / 2), dim3(1024), 0, stream,
                       x, tvec, b_ih, b_hh, W1, b1, W2, b2, WHx, WIx, out);
}

// Round 18
// 1258.188 us; speedup vs baseline: 1.0386x; 1.0386x over previous
//
#include <hip/hip_runtime.h>

// ODE-GRU on MI355X, round 18.
// Chassis = round 16 (256 blocks x 512 thr, dual-row register-amortized,
// f16 dot2, DPP reductions, forward Euler, 3 barriers/step, nontemporal
// out). Changes (latency-shaving only, VALU work unchanged):
//  1. Entire ih weight set (WIx, 96 KB) copied to LDS once at kernel start
//     -> 12 of 60 per-thread L2 loads/step become LDS reads.
//  2. First 2 hh q-chunks per gate (48 KB) also LDS-resident -> 6 more.
//     Total LDS 151 KB < 160 KB, still 1 block/CU.
//  3. dt table precomputed into LDS (removes 2 tvec loads/step).
// Design-space fence (16 rounds of evidence): thread-splitting bloats
// instructions (r10/r17); 2 blocks/CU -> weight refetch storm (r12/r14);
// prefetch depth -> spills (r8/r11/r15); Euler = drift minimum; 3 barriers
// = decomposition floor. If this gains <5%, structural floor reached.

#define SEQ   256
#define BATCH 512
#define DIN   54
#define HDIM  256
#define DH    64

typedef _Float16 h2 __attribute__((ext_vector_type(2)));
typedef _Float16 h8 __attribute__((ext_vector_type(8)));

#define PX(v, p) __builtin_shufflevector((v), (v), 2*(p), 2*(p)+1)

#if defined(__has_builtin)
#  if __has_builtin(__builtin_amdgcn_fdot2)
#    define FDOT2(a, b, c) __builtin_amdgcn_fdot2((a), (b), (c), false)
#  endif
#endif
#ifndef FDOT2
#  define FDOT2(a, b, c) fmaf((float)(a)[0], (float)(b)[0], \
                         fmaf((float)(a)[1], (float)(b)[1], (c)))
#endif

__device__ __forceinline__ float rcp_f(float x) { return __builtin_amdgcn_rcpf(x); }

__device__ __forceinline__ float fast_tanh(float x) {
    x = fminf(15.0f, fmaxf(-15.0f, x));
    float e = __expf(2.0f * x);
    return 1.0f - 2.0f * rcp_f(e + 1.0f);
}
__device__ __forceinline__ float fast_sigmoid(float x) {
    x = fminf(30.0f, fmaxf(-30.0f, x));
    return rcp_f(1.0f + __expf(-x));
}

// x + dpp_permute(x): cross-lane add at VALU latency.
// 0xB1 quad_perm lane^1; 0x4E quad_perm lane^2; 0x141 row_half_mirror
// (8-lane finisher once quad-uniform). Validated r9/r12/r13/r16.
template <int CTRL>
__device__ __forceinline__ float dppadd(float x) {
    return x + __int_as_float(
        __builtin_amdgcn_mov_dpp(__float_as_int(x), CTRL, 0xF, 0xF, true));
}

// 4 dot2: accumulate h8 W . h8 Y into A
#define DOT8(A, W, Y) { \
    A = FDOT2(PX(W,0), PX(Y,0), A); A = FDOT2(PX(W,1), PX(Y,1), A); \
    A = FDOT2(PX(W,2), PX(Y,2), A); A = FDOT2(PX(W,3), PX(Y,3), A); }

// ---- prep: f16 GRU weights in [chunk][thread] coalesced layout (as r13) --
// WHx: 24576 h8. id = g*8192 + q*512 + t ; holds W_hh[j+256g][p*128+q*8 ..+8]
// WIx:  6144 h8. id = g*2048 + q*512 + t ; holds W_ih[j+256g][p*32+q*8 ..+8]
//                (cols >= 54 zero-padded), j=t>>1, p=t&1.
__global__ __launch_bounds__(256)
void prep_kernel(const float* __restrict__ W_ih, const float* __restrict__ W_hh,
                 h8* __restrict__ WHx, h8* __restrict__ WIx)
{
    const int id = blockIdx.x * 256 + threadIdx.x;
    if (id < 24576) {
        const int g = id >> 13, rem = id & 8191;
        const int q = rem >> 9, t = rem & 511;
        const int j = t >> 1, p = t & 1;
        const float* src = W_hh + (size_t)(j + 256 * g) * HDIM + p * 128 + q * 8;
        h8 v;
        #pragma unroll
        for (int e = 0; e < 8; ++e) v[e] = (_Float16)src[e];
        WHx[id] = v;
    } else if (id < 24576 + 6144) {
        const int id2 = id - 24576;
        const int g = id2 >> 11, rem = id2 & 2047;
        const int q = rem >> 9, t = rem & 511;
        const int j = t >> 1, p = t & 1;
        h8 v;
        #pragma unroll
        for (int e = 0; e < 8; ++e) {
            const int col = p * 32 + q * 8 + e;
            v[e] = (col < DIN) ? (_Float16)W_ih[(size_t)(j + 256 * g) * DIN + col]
                               : (_Float16)0.0f;
        }
        WIx[id2] = v;
    }
}

__global__ void
__attribute__((amdgpu_flat_work_group_size(512, 512), amdgpu_waves_per_eu(2, 2)))
odegru_kernel(const float* __restrict__ x,
              const float* __restrict__ tvec,
              const float* __restrict__ b_ih,
              const float* __restrict__ b_hh,
              const float* __restrict__ W1,
              const float* __restrict__ b1,
              const float* __restrict__ W2,
              const float* __restrict__ b2,
              const h8* __restrict__ WHx,
              const h8* __restrict__ WIx,
              float* __restrict__ out)
{
    const int t  = threadIdx.x;          // 0..511
    const int b0 = blockIdx.x * 2;       // batch row A
    const int bB = b0 + 1;               // batch row B
    const int j  = t >> 1;               // element 0..255
    const int p  = t & 1;                // pair half
    const int i1 = t >> 3;               // drift stage1 output 0..63
    const int k8 = t & 7;                // stage1 k-chunk

    __shared__ __align__(16) _Float16 yG0[HDIM], yG1[HDIM];   // GRU-input y
    __shared__ __align__(16) _Float16 yh0[HDIM], yh1[HDIM];   // drift y
    __shared__ __align__(16) _Float16 uh0[DH],  uh1[DH];
    __shared__ __align__(16) _Float16 xh0[64],  xh1[64];
    __shared__ __align__(16) h8 WIL[6144];    // full ih weight set (96 KB)
    __shared__ __align__(16) h8 WHL[3072];    // hh q=0,1 per gate  (48 KB)
    __shared__ float dts[SEQ];

    // ---- one-time LDS staging: ih weights, hh head-chunks, dt table ----
    #pragma unroll
    for (int k = 0; k < 12; ++k) WIL[k * 512 + t] = WIx[k * 512 + t];
    // WHL layout: [gate g][q in 0..1][t] -> (g*2+q)*512 + t
    #pragma unroll
    for (int g = 0; g < 3; ++g) {
        WHL[(g * 2 + 0) * 512 + t] = WHx[(g * 16 + 0) * 512 + t];
        WHL[(g * 2 + 1) * 512 + t] = WHx[(g * 16 + 1) * 512 + t];
    }
    if (t < SEQ)
        dts[t] = (t > 0) ? (tvec[t - 1] - tvec[t]) : 0.0f;

    // Drift weights -> 8 named h8 vars (32 VGPRs), shared by both rows.
    h8 w1m0, w1m1, w1m2, w1m3, w2q0, w2q1, w2q2, w2q3;
    {
        const float* base = W1 + (size_t)i1 * HDIM + k8 * 8;
        h8 v;
        #pragma unroll
        for (int e = 0; e < 8; ++e) v[e] = (_Float16)base[e +   0]; w1m0 = v;
        #pragma unroll
        for (int e = 0; e < 8; ++e) v[e] = (_Float16)base[e +  64]; w1m1 = v;
        #pragma unroll
        for (int e = 0; e < 8; ++e) v[e] = (_Float16)base[e + 128]; w1m2 = v;
        #pragma unroll
        for (int e = 0; e < 8; ++e) v[e] = (_Float16)base[e + 192]; w1m3 = v;
    }
    {
        const float* base = W2 + (size_t)j * DH + p * 32;
        h8 v;
        #pragma unroll
        for (int e = 0; e < 8; ++e) v[e] = (_Float16)base[e +  0]; w2q0 = v;
        #pragma unroll
        for (int e = 0; e < 8; ++e) v[e] = (_Float16)base[e +  8]; w2q1 = v;
        #pragma unroll
        for (int e = 0; e < 8; ++e) v[e] = (_Float16)base[e + 16]; w2q2 = v;
        #pragma unroll
        for (int e = 0; e < 8; ++e) v[e] = (_Float16)base[e + 24]; w2q3 = v;
    }

    const float b1r  = b1[i1];
    const float b2r  = b2[j];
    const float bihr = b_ih[j], bihz = b_ih[j + HDIM], bihn = b_ih[j + 2 * HDIM];
    const float bhhr = b_hh[j], bhhz = b_hh[j + HDIM], bhhn = b_hh[j + 2 * HDIM];

    float h0 = 0.0f, h1 = 0.0f;

    __syncthreads();   // staging barrier (WIL/WHL/dts ready)

    for (int i = 0; i < SEQ; ++i) {
        const int s = SEQ - 1 - i;

        if (t < 64) {
            xh0[t] = (t < DIN) ? (_Float16)x[((size_t)s * BATCH + b0) * DIN + t]
                               : (_Float16)0.0f;
        } else if (t < 128) {
            const int u = t - 64;
            xh1[u] = (u < DIN) ? (_Float16)x[((size_t)s * BATCH + bB) * DIN + u]
                               : (_Float16)0.0f;
        }
        if (p == 0) { yG0[j] = (_Float16)h0; yG1[j] = (_Float16)h1; }
        __syncthreads();                                   // B1 (top)

        // ---- GRU: ih weights from LDS; each load feeds BOTH rows ----
        float xr0 = 0.f, xz0 = 0.f, xn0 = 0.f;
        float xr1 = 0.f, xz1 = 0.f, xn1 = 0.f;
        #pragma unroll
        for (int q = 0; q < 4; ++q) {
            h8 wr = WIL[(0 * 4 + q) * 512 + t];
            h8 wz = WIL[(1 * 4 + q) * 512 + t];
            h8 wn = WIL[(2 * 4 + q) * 512 + t];
            h8 xv0 = *(const h8*)(xh0 + p * 32 + q * 8);
            h8 xv1 = *(const h8*)(xh1 + p * 32 + q * 8);
            DOT8(xr0, wr, xv0) DOT8(xr1, wr, xv1)
            DOT8(xz0, wz, xv0) DOT8(xz1, wz, xv1)
            DOT8(xn0, wn, xv0) DOT8(xn1, wn, xv1)
        }
        float hr0 = 0.f, hz0 = 0.f, hn0 = 0.f;
        float hr1 = 0.f, hz1 = 0.f, hn1 = 0.f;
        #pragma unroll 2
        for (int q = 0; q < 16; ++q) {
            h8 wr = (q < 2) ? WHL[(0 * 2 + q) * 512 + t] : WHx[(0 * 16 + q) * 512 + t];
            h8 wz = (q < 2) ? WHL[(1 * 2 + q) * 512 + t] : WHx[(1 * 16 + q) * 512 + t];
            h8 wn = (q < 2) ? WHL[(2 * 2 + q) * 512 + t] : WHx[(2 * 16 + q) * 512 + t];
            h8 yv0 = *(const h8*)(yG0 + p * 128 + q * 8);
            h8 yv1 = *(const h8*)(yG1 + p * 128 + q * 8);
            DOT8(hr0, wr, yv0) DOT8(hr1, wr, yv1)
            DOT8(hz0, wz, yv0) DOT8(hz1, wz, yv1)
            DOT8(hn0, wn, yv0) DOT8(hn1, wn, yv1)
        }
        {
            float Rp = dppadd<0xB1>(xr0 + hr0);
            float Zp = dppadd<0xB1>(xz0 + hz0);
            float Ip = dppadd<0xB1>(xn0);
            float Hp = dppadd<0xB1>(hn0);
            float r_g = fast_sigmoid(Rp + bihr + bhhr);
            float z_g = fast_sigmoid(Zp + bihz + bhhz);
            float n_g = fast_tanh(Ip + bihn + r_g * (Hp + bhhn));
            h0 = n_g + z_g * (h0 - n_g);
        }
        {
            float Rp = dppadd<0xB1>(xr1 + hr1);
            float Zp = dppadd<0xB1>(xz1 + hz1);
            float Ip = dppadd<0xB1>(xn1);
            float Hp = dppadd<0xB1>(hn1);
            float r_g = fast_sigmoid(Rp + bihr + bhhr);
            float z_g = fast_sigmoid(Zp + bihz + bhhz);
            float n_g = fast_tanh(Ip + bihn + r_g * (Hp + bhhn));
            h1 = n_g + z_g * (h1 - n_g);
        }
        // no barrier: drift writes yh* (not yG*); yG* WAR gap spans B2+B3.

        // ---- ODE integrate: forward Euler (1 dual-row drift) ----
        const float dt = dts[s];

        if (dt != 0.0f) {   // block-uniform; dt==0 only at s==0 (exact skip)
            if (p == 0) { yh0[j] = (_Float16)h0; yh1[j] = (_Float16)h1; }
            __syncthreads();                               // B2
            float a00 = 0.f, a01 = 0.f, a10 = 0.f, a11 = 0.f;
            {
                h8 v;
                v = *(const h8*)(yh0 + k8 * 8 +   0); DOT8(a00, w1m0, v)
                v = *(const h8*)(yh0 + k8 * 8 +  64); DOT8(a01, w1m1, v)
                v = *(const h8*)(yh0 + k8 * 8 + 128); DOT8(a00, w1m2, v)
                v = *(const h8*)(yh0 + k8 * 8 + 192); DOT8(a01, w1m3, v)
                v = *(const h8*)(yh1 + k8 * 8 +   0); DOT8(a10, w1m0, v)
                v = *(const h8*)(yh1 + k8 * 8 +  64); DOT8(a11, w1m1, v)
                v = *(const h8*)(yh1 + k8 * 8 + 128); DOT8(a10, w1m2, v)
                v = *(const h8*)(yh1 + k8 * 8 + 192); DOT8(a11, w1m3, v)
            }
            float as0 = a00 + a01, as1 = a10 + a11;
            as0 = dppadd<0xB1>(as0);  as1 = dppadd<0xB1>(as1);
            as0 = dppadd<0x4E>(as0);  as1 = dppadd<0x4E>(as1);
            as0 = dppadd<0x141>(as0); as1 = dppadd<0x141>(as1);
            float uu0 = fast_tanh(as0 + b1r);
            float uu1 = fast_tanh(as1 + b1r);
            if (k8 == 0) { uh0[i1] = (_Float16)uu0; uh1[i1] = (_Float16)uu1; }
            __syncthreads();                               // B3
            float c00 = 0.f, c01 = 0.f, c10 = 0.f, c11 = 0.f;
            {
                h8 u;
                u = *(const h8*)(uh0 + p * 32 +  0); DOT8(c00, w2q0, u)
                u = *(const h8*)(uh0 + p * 32 +  8); DOT8(c01, w2q1, u)
                u = *(const h8*)(uh0 + p * 32 + 16); DOT8(c00, w2q2, u)
                u = *(const h8*)(uh0 + p * 32 + 24); DOT8(c01, w2q3, u)
                u = *(const h8*)(uh1 + p * 32 +  0); DOT8(c10, w2q0, u)
                u = *(const h8*)(uh1 + p * 32 +  8); DOT8(c11, w2q1, u)
                u = *(const h8*)(uh1 + p * 32 + 16); DOT8(c10, w2q2, u)
                u = *(const h8*)(uh1 + p * 32 + 24); DOT8(c11, w2q3, u)
            }
            float k0 = dppadd<0xB1>(c00 + c01) + b2r;
            float k1 = dppadd<0xB1>(c10 + c11) + b2r;
            h0 = fmaf(dt, k0, h0);
            h1 = fmaf(dt, k1, h1);
        } else {
            __syncthreads();   // degenerate dt: keep next-step writes ordered
        }

        if (p == 0) {
            __builtin_nontemporal_store(h0, &out[((size_t)s * BATCH + b0) * HDIM + j]);
            __builtin_nontemporal_store(h1, &out[((size_t)s * BATCH + bB) * HDIM + j]);
        }
        // no bottom barrier: next top's yG*/xh* writes WAR-safe (gap spans
        // B2+B3 of this step); yh*/uh* gaps span B3+B1 / B1+B2 respectively.
    }
}

extern "C" void kernel_launch(void* const* d_in, const int* in_sizes, int n_in,
                              void* d_out, int out_size, void* d_ws, size_t ws_size,
                              hipStream_t stream) {
    const float* x    = (const float*)d_in[0];
    const float* tvec = (const float*)d_in[1];
    const float* W_ih = (const float*)d_in[2];
    const float* W_hh = (const float*)d_in[3];
    const float* b_ih = (const float*)d_in[4];
    const float* b_hh = (const float*)d_in[5];
    const float* W1   = (const float*)d_in[6];
    const float* b1   = (const float*)d_in[7];
    const float* W2   = (const float*)d_in[8];
    const float* b2   = (const float*)d_in[9];
    float* out = (float*)d_out;

    h8* WHx = (h8*)d_ws;                                   // 24576*16 = 393216 B
    h8* WIx = (h8*)((char*)d_ws + 24576 * 16);             //  6144*16 =  98304 B

    hipLaunchKernelGGL(prep_kernel, dim3(120), dim3(256), 0, stream,
                       W_ih, W_hh, WHx, WIx);
    hipLaunchKernelGGL(odegru_kernel, dim3(BATCH / 2), dim3(512), 0, stream,
                       x, tvec, b_ih, b_hh, W1, b1, W2, b2, WHx, WIx, out);
}